// Round 10
// baseline (764.546 us; speedup 1.0000x reference)
//
#include <hip/hip_runtime.h>

#define BATCH 32768
#define SEQ 30
#define INP 13
#define HID 128
#define ROWS 16
#define NBLK (BATCH/ROWS)        // 2048 blocks, one batch-group each
#define THREADS 512              // 8 waves, each owns 16 cols x both layers

// LDS: wihs (Wih1 frags) 65536 shorts, then ring[4][16][128] XOR-swizzled
#define LDS_WIHS 65536
#define LDS_RING (LDS_WIHS)
#define LDS_SHORTS (LDS_WIHS + 4*2048)
#define LDS_BYTES (LDS_SHORTS*2)   // 147,456 B

typedef float f32x4  __attribute__((ext_vector_type(4)));
typedef short bf16x8 __attribute__((ext_vector_type(8)));

__device__ inline unsigned short f2bf(float f){
  unsigned int u = __float_as_uint(f);
  u = u + 0x7fffu + ((u >> 16) & 1u);   // RNE, finite inputs (R1-R9 proven)
  return (unsigned short)(u >> 16);
}
__device__ inline float exp2_hw(float x){ float r; asm("v_exp_f32 %0, %1" : "=v"(r) : "v"(x)); return r; }
__device__ inline float rcp_hw (float x){ float r; asm("v_rcp_f32 %0, %1" : "=v"(r) : "v"(x)); return r; }
__device__ inline float sigm (float x){ return rcp_hw(1.f + exp2_hw(-1.4426950408889634f*x)); }
__device__ inline float tanh_(float x){ return 1.f - 2.f*rcp_hw(1.f + exp2_hw(2.8853900817779268f*x)); }

// XOR-swizzled ring addressing (pitch 128 shorts = 256B rows; slot = 2048 shorts)
// measured R5/R6/R8/R9: SQ_LDS_BANK_CONFLICT == 0
__device__ inline int ring_rd(int slot, int row, int kshort){
  return slot*2048 + row*128 + (kshort ^ (row<<3));
}
__device__ inline int ring_wr(int slot, int row, int col){
  return slot*2048 + row*128 + (col ^ (row<<3));
}

// ---------- weight pre-conversion: f32 row-major -> bf16 MFMA B-frag layout ----------
__global__ void conv_frag(const float* __restrict__ src, unsigned short* __restrict__ dst,
                          int gates, int K, int nks){
  int tid = blockIdx.x*256 + threadIdx.x;
  int total = gates*8*nks*64;
  if(tid >= total) return;
  int lane = tid & 63; int rest = tid >> 6;
  int ks = rest % nks; rest /= nks;
  int ct = rest & 7;   int g  = rest >> 3;
  int lr = lane & 15, lg = lane >> 4;
  int row = g*128 + ct*16 + lr;
  unsigned short out[8];
  #pragma unroll
  for(int e=0;e<8;e++){
    int k = ks*32 + lg*8 + e;
    float v = (k<K) ? src[(long)row*K + k] : 0.f;
    out[e] = f2bf(v);
  }
  *(uint4*)(dst + (long)tid*8) = *(const uint4*)out;
}

__global__ void conv_bias(const float* __restrict__ bih0, const float* __restrict__ bhh0,
                          const float* __restrict__ bih1, const float* __restrict__ bhh1,
                          float* __restrict__ dst){
  int i = blockIdx.x*256 + threadIdx.x;   // 1024 total
  if(i < 512)       dst[i] = bih0[i] + bhh0[i];
  else if(i < 1024) dst[i] = bih1[i-512] + bhh1[i-512];
}

// ---------- x pre-stage: f32 [B][T][13] -> bf16 A-frag layout [t][blk][lane*8] ----------
__global__ __launch_bounds__(256)
void stage_x(const float* __restrict__ x, unsigned short* __restrict__ xf){
  __shared__ float xt[ROWS*SEQ*INP];    // 6240 floats
  const int blk = blockIdx.x, tid = threadIdx.x;
  for(int i=tid; i<ROWS*SEQ*INP; i+=256) xt[i] = x[(long)blk*ROWS*SEQ*INP + i];
  __syncthreads();
  for(int j=tid; j<SEQ*64; j+=256){
    int t = j>>6, lane = j&63, lr = lane&15, lg = lane>>4;
    unsigned short out[8];
    #pragma unroll
    for(int e=0;e<8;e++){
      int k = lg*8+e;
      float v = (k<INP) ? xt[lr*(SEQ*INP) + t*INP + k] : 0.f;
      out[e] = f2bf(v);
    }
    *(uint4*)(xf + (((long)t*NBLK + blk)*64 + lane)*8) = *(const uint4*)out;
  }
}

// ---------- fused 2-layer pipelined LSTM + FC + BN partials ----------
// R4 grid structure (2048 blocks, inter-block overlap) + XOR rings + safe prefetch.
__global__
__attribute__((amdgpu_flat_work_group_size(THREADS, THREADS)))
__attribute__((amdgpu_waves_per_eu(2, 2)))
void lstm_pipe(const unsigned short* __restrict__ xf,
               const unsigned short* __restrict__ whh0f, const unsigned short* __restrict__ wih0f,
               const unsigned short* __restrict__ wih1f, const unsigned short* __restrict__ whh1f,
               const unsigned short* __restrict__ fcf,   const float* __restrict__ biases,
               const float* __restrict__ fcb,
               float* __restrict__ y, float* __restrict__ partial)
{
  extern __shared__ unsigned short lds[];
  unsigned short* wihs = lds;               // 128 KB Wih1 frags
  unsigned short* ring = lds + LDS_RING;    // 16 KB swizzled rings

  const int tid=threadIdx.x, lane=tid&63, wv=tid>>6, lr=lane&15, lg=lane>>4;
  const int myc = wv*16 + lr;
  const int blk = blockIdx.x, row0 = blk*ROWS;

  // stage Wih1 frags into LDS (linear, coalesced)
  {
    const uint4* src4 = (const uint4*)wih1f;
    uint4* dst4 = (uint4*)lds;
    #pragma unroll
    for(int i=0;i<16;++i) dst4[tid + i*THREADS] = src4[tid + i*THREADS];
  }

  // register-resident weights (pre-converted)
  bf16x8 w0h[4][4], w1h[4][4], w0i[4];
  float bias0[4], bias1[4];
  #pragma unroll
  for(int g=0; g<4; ++g){
    #pragma unroll
    for(int ks=0; ks<4; ++ks){
      long off = (long)((((g*8+wv)*4+ks)*64+lane))*8;
      w0h[g][ks] = *(const bf16x8*)(whh0f + off);
      w1h[g][ks] = *(const bf16x8*)(whh1f + off);
    }
    w0i[g] = *(const bf16x8*)(wih0f + (long)(((g*8+wv)*64+lane))*8);
    bias0[g] = biases[g*HID+myc];
    bias1[g] = biases[512 + g*HID+myc];
  }
  float c1[4]={0,0,0,0}, c2[4]={0,0,0,0};
  f32x4 acc1[4];
  bf16x8 ax = *(const bf16x8*)(xf + ((long)blk*64 + lane)*8);   // x_0
  __syncthreads();   // wihs staged

  for(int tau=0; tau<=SEQ; ++tau){
    const int s_prev = (tau-1)&1;
    // prefetch next x-frag (boundary-safe index: always initialized)
    const int tnext = (tau+1 < SEQ) ? (tau+1) : (SEQ-1);
    bf16x8 ax_n = *(const bf16x8*)(xf + (((long)tnext*NBLK + blk)*64 + lane)*8);
    // h1_{tau-1} A-frags (shared by L1 input path and L0 recurrence)
    bf16x8 a1[4];
    if(tau>=1){
      #pragma unroll
      for(int ks=0;ks<4;++ks)
        a1[ks] = *(const bf16x8*)(ring + ring_rd(s_prev, lr, ks*32+lg*8));
    }
    // ---- layer 1 (computes h2_{tau-1}) ----
    if(tau>=1){
      #pragma unroll
      for(int g=0;g<4;++g) acc1[g]=(f32x4){bias1[g],bias1[g],bias1[g],bias1[g]};
      #pragma unroll
      for(int ks=0;ks<4;++ks){
        #pragma unroll
        for(int g=0;g<4;++g){
          bf16x8 wf = *(const bf16x8*)(wihs + (long)((((g*8+wv)*4+ks)*64+lane))*8);
          acc1[g]=__builtin_amdgcn_mfma_f32_16x16x32_bf16(a1[ks],wf,acc1[g],0,0,0);
        }
      }
      if(tau>=2){
        #pragma unroll
        for(int ks=0;ks<4;++ks){
          bf16x8 a2 = *(const bf16x8*)(ring + ring_rd(2+(tau&1), lr, ks*32+lg*8));
          #pragma unroll
          for(int g=0;g<4;++g)
            acc1[g]=__builtin_amdgcn_mfma_f32_16x16x32_bf16(a2,w1h[g][ks],acc1[g],0,0,0);
        }
      }
    }
    // ---- layer 0 (computes h1_tau) ----
    f32x4 acc0[4];
    if(tau<SEQ){
      #pragma unroll
      for(int g=0;g<4;++g){
        acc0[g]=(f32x4){bias0[g],bias0[g],bias0[g],bias0[g]};
        acc0[g]=__builtin_amdgcn_mfma_f32_16x16x32_bf16(ax,w0i[g],acc0[g],0,0,0);
      }
      if(tau>=1){
        #pragma unroll
        for(int ks=0;ks<4;++ks)
          #pragma unroll
          for(int g=0;g<4;++g)
            acc0[g]=__builtin_amdgcn_mfma_f32_16x16x32_bf16(a1[ks],w0h[g][ks],acc0[g],0,0,0);
      }
    }
    // ---- activations ----
    if(tau<SEQ){
      #pragma unroll
      for(int r=0;r<4;++r){
        float iv=sigm(acc0[0][r]), fv=sigm(acc0[1][r]), gv=tanh_(acc0[2][r]), ov=sigm(acc0[3][r]);
        c1[r]=fv*c1[r]+iv*gv;
        ring[ring_wr(tau&1, lg*4+r, myc)] = f2bf(ov*tanh_(c1[r]));
      }
    }
    if(tau>=1){
      #pragma unroll
      for(int r=0;r<4;++r){
        float iv=sigm(acc1[0][r]), fv=sigm(acc1[1][r]), gv=tanh_(acc1[2][r]), ov=sigm(acc1[3][r]);
        c2[r]=fv*c2[r]+iv*gv;
        ring[ring_wr(2+s_prev, lg*4+r, myc)] = f2bf(ov*tanh_(c2[r]));
      }
    }
    ax = ax_n;
    __syncthreads();
  }

  // ---- FC + BN partials; h2[SEQ-1] in slot 2+((SEQ-1)&1) = 3 ----
  {
    f32x4 ay=(f32x4){fcb[myc],fcb[myc],fcb[myc],fcb[myc]};
    #pragma unroll
    for(int ks=0;ks<4;++ks){
      bf16x8 bfc = *(const bf16x8*)(fcf + (long)(((wv*4+ks)*64+lane))*8);
      bf16x8 a2  = *(const bf16x8*)(ring + ring_rd(3, lr, ks*32+lg*8));
      ay=__builtin_amdgcn_mfma_f32_16x16x32_bf16(a2,bfc,ay,0,0,0);
    }
    float s=0.f, sq=0.f;
    #pragma unroll
    for(int r=0;r<4;++r){
      float v=ay[r];
      y[(long)(row0+lg*4+r)*HID+myc]=v;
      s+=v; sq+=v*v;
    }
    s +=__shfl_xor(s ,16,64); s +=__shfl_xor(s ,32,64);
    sq+=__shfl_xor(sq,16,64); sq+=__shfl_xor(sq,32,64);
    if(lg==0){
      partial[(long)myc      *NBLK+blk]=s;
      partial[(long)(HID+myc)*NBLK+blk]=sq;
    }
  }
}

// ---------------- BN reduce / apply ----------------
__global__ void bn_reduce(const float* __restrict__ partial, float* __restrict__ mv){
  int c=blockIdx.x;
  float s=0.f,sq=0.f;
  for(int i=threadIdx.x;i<NBLK;i+=256){
    s +=partial[(long)c      *NBLK+i];
    sq+=partial[(long)(HID+c)*NBLK+i];
  }
  #pragma unroll
  for(int m=32;m>=1;m>>=1){ s+=__shfl_xor(s,m,64); sq+=__shfl_xor(sq,m,64); }
  __shared__ float rs[4],rq[4];
  int w=threadIdx.x>>6;
  if((threadIdx.x&63)==0){ rs[w]=s; rq[w]=sq; }
  __syncthreads();
  if(threadIdx.x==0){
    s=rs[0]+rs[1]+rs[2]+rs[3]; sq=rq[0]+rq[1]+rq[2]+rq[3];
    float mean=s/(float)BATCH;
    float var=sq/(float)BATCH-mean*mean;
    mv[c]=mean; mv[HID+c]=rsqrtf(var+1e-5f);
  }
}

__global__ void bn_apply(float* __restrict__ y, const float* __restrict__ mv,
                         const float* __restrict__ gamma, const float* __restrict__ beta){
  long idx=((long)blockIdx.x*256+threadIdx.x)*4;
  int c=(int)(idx&(HID-1));
  float4 v=*reinterpret_cast<float4*>(y+idx);
  v.x=gamma[c+0]*(v.x-mv[c+0])*mv[HID+c+0]+beta[c+0];
  v.y=gamma[c+1]*(v.y-mv[c+1])*mv[HID+c+1]+beta[c+1];
  v.z=gamma[c+2]*(v.z-mv[c+2])*mv[HID+c+2]+beta[c+2];
  v.w=gamma[c+3]*(v.w-mv[c+3])*mv[HID+c+3]+beta[c+3];
  *reinterpret_cast<float4*>(y+idx)=v;
}

extern "C" void kernel_launch(void* const* d_in, const int* in_sizes, int n_in,
                              void* d_out, int out_size, void* d_ws, size_t ws_size,
                              hipStream_t stream){
  const float* x    =(const float*)d_in[0];
  const float* Wih0 =(const float*)d_in[1];
  const float* Whh0 =(const float*)d_in[2];
  const float* bih0 =(const float*)d_in[3];
  const float* bhh0 =(const float*)d_in[4];
  const float* Wih1 =(const float*)d_in[5];
  const float* Whh1 =(const float*)d_in[6];
  const float* bih1 =(const float*)d_in[7];
  const float* bhh1 =(const float*)d_in[8];
  const float* fcW  =(const float*)d_in[9];
  const float* fcb  =(const float*)d_in[10];
  const float* gamma=(const float*)d_in[11];
  const float* beta =(const float*)d_in[12];
  float* y=(float*)d_out;

  // ws layout (bytes)
  char* ws = (char*)d_ws;
  const long XF_BYTES = (long)SEQ*NBLK*64*8*2;              // 62,914,560
  unsigned short* xf    = (unsigned short*)(ws + 0);
  unsigned short* whh0f = (unsigned short*)(ws + XF_BYTES);             // 131072 B
  unsigned short* wih0f = (unsigned short*)(ws + XF_BYTES + 131072);    //  32768 B
  unsigned short* wih1f = (unsigned short*)(ws + XF_BYTES + 163840);    // 131072 B
  unsigned short* whh1f = (unsigned short*)(ws + XF_BYTES + 294912);    // 131072 B
  unsigned short* fcf   = (unsigned short*)(ws + XF_BYTES + 425984);    //  32768 B
  float*          biases= (float*)         (ws + XF_BYTES + 458752);    //   4096 B
  float*          partial=(float*)         (ws + XF_BYTES + 462848);    // 2 MB
  float*          mv    = partial + (long)2*HID*NBLK;

  conv_frag<<<32,256,0,stream>>>(Whh0, whh0f, 4, HID, 4);
  conv_frag<<<8, 256,0,stream>>>(Wih0, wih0f, 4, INP, 1);
  conv_frag<<<32,256,0,stream>>>(Wih1, wih1f, 4, HID, 4);
  conv_frag<<<32,256,0,stream>>>(Whh1, whh1f, 4, HID, 4);
  conv_frag<<<8, 256,0,stream>>>(fcW,  fcf,   1, HID, 4);
  conv_bias<<<4, 256,0,stream>>>(bih0,bhh0,bih1,bhh1,biases);
  stage_x<<<NBLK,256,0,stream>>>(x, xf);

  hipFuncSetAttribute((const void*)lstm_pipe,
                      hipFuncAttributeMaxDynamicSharedMemorySize, LDS_BYTES);
  lstm_pipe<<<NBLK,THREADS,LDS_BYTES,stream>>>(
      xf, whh0f, wih0f, wih1f, whh1f, fcf, biases, fcb, y, partial);
  bn_reduce<<<HID,256,0,stream>>>(partial,mv);
  bn_apply<<<(BATCH*HID)/(256*4),256,0,stream>>>(y,mv,gamma,beta);
}

// Round 11
// 541.832 us; speedup vs baseline: 1.4110x; 1.4110x over previous
//
#include <hip/hip_runtime.h>

#define BATCH 32768
#define SEQ 30
#define INP 13
#define HID 128
#define ROWS 16
#define NBLK (BATCH/ROWS)        // 2048 blocks
#define THREADS 512              // 8 waves
#define H1PITCH 136              // shorts per row (128 + 8 pad)
#define H1SLOT (ROWS*H1PITCH)    // 2176 shorts per ring slot

// LDS: [0,65536) wih1 frags (shorts), then h1ring[2], h2ring[2]
#define LDS_WIH1 65536
#define LDS_H1   (LDS_WIH1)
#define LDS_H2   (LDS_WIH1 + 2*H1SLOT)
#define LDS_SHORTS (LDS_WIH1 + 4*H1SLOT)
#define LDS_BYTES (LDS_SHORTS*2)   // 148,480 B

typedef float f32x4  __attribute__((ext_vector_type(4)));
typedef short bf16x8 __attribute__((ext_vector_type(8)));

__device__ inline unsigned short f2bf(float f){
  unsigned int u = __float_as_uint(f);
  u = u + 0x7fffu + ((u >> 16) & 1u);   // RNE, finite inputs
  return (unsigned short)(u >> 16);
}
__device__ inline float exp2_hw(float x){ float r; asm("v_exp_f32 %0, %1" : "=v"(r) : "v"(x)); return r; }
__device__ inline float rcp_hw (float x){ float r; asm("v_rcp_f32 %0, %1" : "=v"(r) : "v"(x)); return r; }
__device__ inline float sigm (float x){ return rcp_hw(1.f + exp2_hw(-1.4426950408889634f*x)); }
__device__ inline float tanh_(float x){ return 1.f - 2.f*rcp_hw(1.f + exp2_hw(2.8853900817779268f*x)); }

// ---------- weight pre-conversion: f32 row-major -> bf16 MFMA B-frag layout ----------
__global__ void conv_frag(const float* __restrict__ src, unsigned short* __restrict__ dst,
                          int gates, int K, int nks){
  int tid = blockIdx.x*256 + threadIdx.x;
  int total = gates*8*nks*64;
  if(tid >= total) return;
  int lane = tid & 63; int rest = tid >> 6;
  int ks = rest % nks; rest /= nks;
  int ct = rest & 7;   int g  = rest >> 3;
  int lr = lane & 15, lg = lane >> 4;
  int row = g*128 + ct*16 + lr;
  unsigned short out[8];
  #pragma unroll
  for(int e=0;e<8;e++){
    int k = ks*32 + lg*8 + e;
    float v = (k<K) ? src[(long)row*K + k] : 0.f;
    out[e] = f2bf(v);
  }
  *(uint4*)(dst + (long)tid*8) = *(const uint4*)out;
}

__global__ void conv_bias(const float* __restrict__ bih0, const float* __restrict__ bhh0,
                          const float* __restrict__ bih1, const float* __restrict__ bhh1,
                          float* __restrict__ dst){
  int i = blockIdx.x*256 + threadIdx.x;   // 1024 total
  if(i < 512)       dst[i] = bih0[i] + bhh0[i];
  else if(i < 1024) dst[i] = bih1[i-512] + bhh1[i-512];
}

// ---------- x pre-stage: f32 [B][T][13] -> bf16 A-frag layout [t][blk][lane*8] ----------
__global__ __launch_bounds__(256)
void stage_x(const float* __restrict__ x, unsigned short* __restrict__ xf){
  __shared__ float xt[ROWS*SEQ*INP];    // 16*390 = 6240 floats, 25 KB
  const int blk = blockIdx.x, tid = threadIdx.x;
  for(int i=tid; i<ROWS*SEQ*INP; i+=256) xt[i] = x[(long)blk*ROWS*SEQ*INP + i];
  __syncthreads();
  for(int j=tid; j<SEQ*64; j+=256){
    int t = j>>6, lane = j&63, lr = lane&15, lg = lane>>4;
    unsigned short out[8];
    #pragma unroll
    for(int e=0;e<8;e++){
      int k = lg*8+e;
      float v = (k<INP) ? xt[lr*(SEQ*INP) + t*INP + k] : 0.f;
      out[e] = f2bf(v);
    }
    *(uint4*)(xf + (((long)t*NBLK + blk)*64 + lane)*8) = *(const uint4*)out;
  }
}

// ---------- fused 2-layer pipelined LSTM + FC + BN partials ----------
// Byte-exact R4 body (best measured codegen: 592 us). Single change: request a
// 256-VGPR budget explicitly. LDS (148 KB) already caps residency at 1 block/CU
// (8 waves = 2/SIMD), so 256 regs costs zero occupancy; the allocator's 128-reg
// heuristic was causing ~100 regs of scratch spill (R8-R10: 90-190 MB traffic).
__global__
__attribute__((amdgpu_flat_work_group_size(THREADS, THREADS)))
__attribute__((amdgpu_num_vgpr(256)))
void lstm_pipe(const unsigned short* __restrict__ xf,
               const unsigned short* __restrict__ whh0f, const unsigned short* __restrict__ wih0f,
               const unsigned short* __restrict__ wih1f, const unsigned short* __restrict__ whh1f,
               const unsigned short* __restrict__ fcf,   const float* __restrict__ biases,
               const float* __restrict__ fcb,
               float* __restrict__ y, float* __restrict__ partial)
{
  extern __shared__ unsigned short lds[];
  unsigned short* wihs = lds;             // 128 KB Wih1 frags
  unsigned short* h1r  = lds + LDS_H1;
  unsigned short* h2r  = lds + LDS_H2;

  const int tid=threadIdx.x, lane=tid&63, wv=tid>>6, lr=lane&15, lg=lane>>4;
  const int blk=blockIdx.x, row0=blk*ROWS, myc=wv*16+lr;

  // stage Wih1 frags into LDS (linear, coalesced)
  {
    const uint4* src4 = (const uint4*)wih1f;
    uint4* dst4 = (uint4*)lds;
    #pragma unroll
    for(int i=0;i<16;++i) dst4[tid + i*THREADS] = src4[tid + i*THREADS];
  }

  // resident weight fragments (pre-converted, single b128 loads)
  bf16x8 w0h[4][4], w1h[4][4], w0i[4];
  float bias0[4], bias1[4];
  #pragma unroll
  for(int g=0; g<4; ++g){
    #pragma unroll
    for(int ks=0; ks<4; ++ks){
      long off = (long)((((g*8+wv)*4+ks)*64+lane))*8;
      w0h[g][ks] = *(const bf16x8*)(whh0f + off);
      w1h[g][ks] = *(const bf16x8*)(whh1f + off);
    }
    w0i[g] = *(const bf16x8*)(wih0f + (long)(((g*8+wv)*64+lane))*8);
    bias0[g] = biases[g*HID+myc];
    bias1[g] = biases[512 + g*HID+myc];
  }
  float c1[4]={0,0,0,0}, c2[4]={0,0,0,0};
  __syncthreads();   // Wih1 staged

  f32x4 acc1[4];
  for(int tau=0; tau<=SEQ; ++tau){
    const int s_prev = (tau-1)&1;
    // x-frag load (coalesced b128, consumed by layer-0 MFMAs)
    bf16x8 ax;
    if(tau<SEQ) ax = *(const bf16x8*)(xf + (((long)tau*NBLK + blk)*64 + lane)*8);
    // shared A-frags: h1_{tau-1} (layer1 input path AND layer0 recurrence)
    bf16x8 a1[4];
    if(tau>=1){
      #pragma unroll
      for(int ks=0;ks<4;++ks)
        a1[ks] = *(const bf16x8*)(h1r + s_prev*H1SLOT + lr*H1PITCH + ks*32 + lg*8);
    }
    // ---- layer 1 (computes h2_{tau-1}) ----
    if(tau>=1){
      #pragma unroll
      for(int g=0;g<4;++g) acc1[g]=(f32x4){bias1[g],bias1[g],bias1[g],bias1[g]};
      #pragma unroll
      for(int ks=0;ks<4;++ks){
        #pragma unroll
        for(int g=0;g<4;++g){
          bf16x8 wf = *(const bf16x8*)(wihs + (long)((((g*8+wv)*4+ks)*64+lane))*8);
          acc1[g]=__builtin_amdgcn_mfma_f32_16x16x32_bf16(a1[ks],wf,acc1[g],0,0,0);
        }
      }
      if(tau>=2){
        #pragma unroll
        for(int ks=0;ks<4;++ks){
          bf16x8 a2 = *(const bf16x8*)(h2r + (tau&1)*H1SLOT + lr*H1PITCH + ks*32 + lg*8);
          #pragma unroll
          for(int g=0;g<4;++g)
            acc1[g]=__builtin_amdgcn_mfma_f32_16x16x32_bf16(a2,w1h[g][ks],acc1[g],0,0,0);
        }
      }
    }
    // ---- layer 0 (computes h1_tau) ----
    f32x4 acc0[4];
    if(tau<SEQ){
      #pragma unroll
      for(int g=0;g<4;++g){
        acc0[g]=(f32x4){bias0[g],bias0[g],bias0[g],bias0[g]};
        acc0[g]=__builtin_amdgcn_mfma_f32_16x16x32_bf16(ax,w0i[g],acc0[g],0,0,0);
      }
      if(tau>=1){
        #pragma unroll
        for(int ks=0;ks<4;++ks)
          #pragma unroll
          for(int g=0;g<4;++g)
            acc0[g]=__builtin_amdgcn_mfma_f32_16x16x32_bf16(a1[ks],w0h[g][ks],acc0[g],0,0,0);
      }
    }
    // ---- activations + ring writes (two independent chains) ----
    if(tau<SEQ){
      #pragma unroll
      for(int r=0;r<4;++r){
        float iv=sigm(acc0[0][r]), fv=sigm(acc0[1][r]), gv=tanh_(acc0[2][r]), ov=sigm(acc0[3][r]);
        c1[r]=fv*c1[r]+iv*gv;
        h1r[(tau&1)*H1SLOT + (lg*4+r)*H1PITCH + myc] = f2bf(ov*tanh_(c1[r]));
      }
    }
    if(tau>=1){
      #pragma unroll
      for(int r=0;r<4;++r){
        float iv=sigm(acc1[0][r]), fv=sigm(acc1[1][r]), gv=tanh_(acc1[2][r]), ov=sigm(acc1[3][r]);
        c2[r]=fv*c2[r]+iv*gv;
        h2r[s_prev*H1SLOT + (lg*4+r)*H1PITCH + myc] = f2bf(ov*tanh_(c2[r]));
      }
    }
    __syncthreads();
  }

  // ---- FC epilogue on h2_{SEQ-1} (ring slot (SEQ-1)&1 == 1) ----
  f32x4 ay=(f32x4){fcb[myc],fcb[myc],fcb[myc],fcb[myc]};
  #pragma unroll
  for(int ks=0;ks<4;++ks){
    bf16x8 bfc = *(const bf16x8*)(fcf + (long)(((wv*4+ks)*64+lane))*8);
    bf16x8 a2  = *(const bf16x8*)(h2r + 1*H1SLOT + lr*H1PITCH + ks*32 + lg*8);
    ay=__builtin_amdgcn_mfma_f32_16x16x32_bf16(a2,bfc,ay,0,0,0);
  }
  float s=0.f, sq=0.f;
  #pragma unroll
  for(int r=0;r<4;++r){
    float v=ay[r];
    y[(long)(row0+lg*4+r)*HID+myc]=v;
    s+=v; sq+=v*v;
  }
  s +=__shfl_xor(s ,16,64); s +=__shfl_xor(s ,32,64);
  sq+=__shfl_xor(sq,16,64); sq+=__shfl_xor(sq,32,64);
  if(lg==0){
    partial[(long)myc      *NBLK+blk]=s;
    partial[(long)(HID+myc)*NBLK+blk]=sq;
  }
}

// ---------------- BN reduce / apply ----------------
__global__ void bn_reduce(const float* __restrict__ partial, float* __restrict__ mv){
  int c=blockIdx.x;
  float s=0.f,sq=0.f;
  for(int i=threadIdx.x;i<NBLK;i+=256){
    s +=partial[(long)c      *NBLK+i];
    sq+=partial[(long)(HID+c)*NBLK+i];
  }
  #pragma unroll
  for(int m=32;m>=1;m>>=1){ s+=__shfl_xor(s,m,64); sq+=__shfl_xor(sq,m,64); }
  __shared__ float rs[4],rq[4];
  int w=threadIdx.x>>6;
  if((threadIdx.x&63)==0){ rs[w]=s; rq[w]=sq; }
  __syncthreads();
  if(threadIdx.x==0){
    s=rs[0]+rs[1]+rs[2]+rs[3]; sq=rq[0]+rq[1]+rq[2]+rq[3];
    float mean=s/(float)BATCH;
    float var=sq/(float)BATCH-mean*mean;
    mv[c]=mean; mv[HID+c]=rsqrtf(var+1e-5f);
  }
}

__global__ void bn_apply(float* __restrict__ y, const float* __restrict__ mv,
                         const float* __restrict__ gamma, const float* __restrict__ beta){
  long idx=((long)blockIdx.x*256+threadIdx.x)*4;
  int c=(int)(idx&(HID-1));
  float4 v=*reinterpret_cast<float4*>(y+idx);
  v.x=gamma[c+0]*(v.x-mv[c+0])*mv[HID+c+0]+beta[c+0];
  v.y=gamma[c+1]*(v.y-mv[c+1])*mv[HID+c+1]+beta[c+1];
  v.z=gamma[c+2]*(v.z-mv[c+2])*mv[HID+c+2]+beta[c+2];
  v.w=gamma[c+3]*(v.w-mv[c+3])*mv[HID+c+3]+beta[c+3];
  *reinterpret_cast<float4*>(y+idx)=v;
}

extern "C" void kernel_launch(void* const* d_in, const int* in_sizes, int n_in,
                              void* d_out, int out_size, void* d_ws, size_t ws_size,
                              hipStream_t stream){
  const float* x    =(const float*)d_in[0];
  const float* Wih0 =(const float*)d_in[1];
  const float* Whh0 =(const float*)d_in[2];
  const float* bih0 =(const float*)d_in[3];
  const float* bhh0 =(const float*)d_in[4];
  const float* Wih1 =(const float*)d_in[5];
  const float* Whh1 =(const float*)d_in[6];
  const float* bih1 =(const float*)d_in[7];
  const float* bhh1 =(const float*)d_in[8];
  const float* fcW  =(const float*)d_in[9];
  const float* fcb  =(const float*)d_in[10];
  const float* gamma=(const float*)d_in[11];
  const float* beta =(const float*)d_in[12];
  float* y=(float*)d_out;

  // ws layout (bytes)
  char* ws = (char*)d_ws;
  const long XF_BYTES = (long)SEQ*NBLK*64*8*2;              // 62,914,560
  unsigned short* xf    = (unsigned short*)(ws + 0);
  unsigned short* whh0f = (unsigned short*)(ws + XF_BYTES);             // 131072 B
  unsigned short* wih0f = (unsigned short*)(ws + XF_BYTES + 131072);    //  32768 B
  unsigned short* wih1f = (unsigned short*)(ws + XF_BYTES + 163840);    // 131072 B
  unsigned short* whh1f = (unsigned short*)(ws + XF_BYTES + 294912);    // 131072 B
  unsigned short* fcf   = (unsigned short*)(ws + XF_BYTES + 425984);    //  32768 B
  float*          biases= (float*)         (ws + XF_BYTES + 458752);    //   4096 B
  float*          partial=(float*)         (ws + XF_BYTES + 462848);    // 2 MB
  float*          mv    = partial + (long)2*HID*NBLK;

  conv_frag<<<32,256,0,stream>>>(Whh0, whh0f, 4, HID, 4);
  conv_frag<<<8, 256,0,stream>>>(Wih0, wih0f, 4, INP, 1);
  conv_frag<<<32,256,0,stream>>>(Wih1, wih1f, 4, HID, 4);
  conv_frag<<<32,256,0,stream>>>(Whh1, whh1f, 4, HID, 4);
  conv_frag<<<8, 256,0,stream>>>(fcW,  fcf,   1, HID, 4);
  conv_bias<<<4, 256,0,stream>>>(bih0,bhh0,bih1,bhh1,biases);
  stage_x<<<NBLK,256,0,stream>>>(x, xf);

  hipFuncSetAttribute((const void*)lstm_pipe,
                      hipFuncAttributeMaxDynamicSharedMemorySize, LDS_BYTES);
  lstm_pipe<<<NBLK,THREADS,LDS_BYTES,stream>>>(
      xf, whh0f, wih0f, wih1f, whh1f, fcf, biases, fcb, y, partial);
  bn_reduce<<<HID,256,0,stream>>>(partial,mv);
  bn_apply<<<(BATCH*HID)/(256*4),256,0,stream>>>(y,mv,gamma,beta);
}

// Round 14
// 541.718 us; speedup vs baseline: 1.4113x; 1.0002x over previous
//
#include <hip/hip_runtime.h>

#define BATCH 32768
#define SEQ 30
#define INP 13
#define HID 128
#define ROWS 16
#define NBLK (BATCH/ROWS)        // 2048 blocks
#define THREADS 512              // 8 waves
#define H1PITCH 136              // shorts per row (128 + 8 pad)
#define H1SLOT (ROWS*H1PITCH)    // 2176 shorts per ring slot

// LDS: [0,65536) wih1 frags (shorts), then h1ring[2], h2ring[2]
#define LDS_WIH1 65536
#define LDS_H1   (LDS_WIH1)
#define LDS_H2   (LDS_WIH1 + 2*H1SLOT)
#define LDS_SHORTS (LDS_WIH1 + 4*H1SLOT)
#define LDS_BYTES (LDS_SHORTS*2)   // 148,480 B

typedef float f32x4  __attribute__((ext_vector_type(4)));
typedef short bf16x8 __attribute__((ext_vector_type(8)));

__device__ inline unsigned short f2bf(float f){
  unsigned int u = __float_as_uint(f);
  u = u + 0x7fffu + ((u >> 16) & 1u);   // RNE, finite inputs
  return (unsigned short)(u >> 16);
}
__device__ inline float exp2_hw(float x){ float r; asm("v_exp_f32 %0, %1" : "=v"(r) : "v"(x)); return r; }
__device__ inline float rcp_hw (float x){ float r; asm("v_rcp_f32 %0, %1" : "=v"(r) : "v"(x)); return r; }
__device__ inline float sigm (float x){ return rcp_hw(1.f + exp2_hw(-1.4426950408889634f*x)); }
__device__ inline float tanh_(float x){ return 1.f - 2.f*rcp_hw(1.f + exp2_hw(2.8853900817779268f*x)); }

// ---------- weight pre-conversion: f32 row-major -> bf16 MFMA B-frag layout ----------
__global__ void conv_frag(const float* __restrict__ src, unsigned short* __restrict__ dst,
                          int gates, int K, int nks){
  int tid = blockIdx.x*256 + threadIdx.x;
  int total = gates*8*nks*64;
  if(tid >= total) return;
  int lane = tid & 63; int rest = tid >> 6;
  int ks = rest % nks; rest /= nks;
  int ct = rest & 7;   int g  = rest >> 3;
  int lr = lane & 15, lg = lane >> 4;
  int row = g*128 + ct*16 + lr;
  unsigned short out[8];
  #pragma unroll
  for(int e=0;e<8;e++){
    int k = ks*32 + lg*8 + e;
    float v = (k<K) ? src[(long)row*K + k] : 0.f;
    out[e] = f2bf(v);
  }
  *(uint4*)(dst + (long)tid*8) = *(const uint4*)out;
}

__global__ void conv_bias(const float* __restrict__ bih0, const float* __restrict__ bhh0,
                          const float* __restrict__ bih1, const float* __restrict__ bhh1,
                          float* __restrict__ dst){
  int i = blockIdx.x*256 + threadIdx.x;   // 1024 total
  if(i < 512)       dst[i] = bih0[i] + bhh0[i];
  else if(i < 1024) dst[i] = bih1[i-512] + bhh1[i-512];
}

// ---------- x pre-stage: f32 [B][T][13] -> bf16 A-frag layout [t][blk][lane*8] ----------
__global__ __launch_bounds__(256)
void stage_x(const float* __restrict__ x, unsigned short* __restrict__ xf){
  __shared__ float xt[ROWS*SEQ*INP];    // 16*390 = 6240 floats, 25 KB
  const int blk = blockIdx.x, tid = threadIdx.x;
  for(int i=tid; i<ROWS*SEQ*INP; i+=256) xt[i] = x[(long)blk*ROWS*SEQ*INP + i];
  __syncthreads();
  for(int j=tid; j<SEQ*64; j+=256){
    int t = j>>6, lane = j&63, lr = lane&15, lg = lane>>4;
    unsigned short out[8];
    #pragma unroll
    for(int e=0;e<8;e++){
      int k = lg*8+e;
      float v = (k<INP) ? xt[lr*(SEQ*INP) + t*INP + k] : 0.f;
      out[e] = f2bf(v);
    }
    *(uint4*)(xf + (((long)t*NBLK + blk)*64 + lane)*8) = *(const uint4*)out;
  }
}

// ---------- fused 2-layer pipelined LSTM + FC + BN partials ----------
// R11 byte-exact: best measured codegen draw (lstm_pipe 592 us, e2e 542 us).
// MfmaUtil 31% + VALUBusy 55% = 86% combined issue; MFMA time at theoretical
// floor (180 us); VALU dominated by irreducible LSTM transcendentals.
__global__
__attribute__((amdgpu_flat_work_group_size(THREADS, THREADS)))
__attribute__((amdgpu_num_vgpr(256)))
void lstm_pipe(const unsigned short* __restrict__ xf,
               const unsigned short* __restrict__ whh0f, const unsigned short* __restrict__ wih0f,
               const unsigned short* __restrict__ wih1f, const unsigned short* __restrict__ whh1f,
               const unsigned short* __restrict__ fcf,   const float* __restrict__ biases,
               const float* __restrict__ fcb,
               float* __restrict__ y, float* __restrict__ partial)
{
  extern __shared__ unsigned short lds[];
  unsigned short* wihs = lds;             // 128 KB Wih1 frags
  unsigned short* h1r  = lds + LDS_H1;
  unsigned short* h2r  = lds + LDS_H2;

  const int tid=threadIdx.x, lane=tid&63, wv=tid>>6, lr=lane&15, lg=lane>>4;
  const int blk=blockIdx.x, row0=blk*ROWS, myc=wv*16+lr;

  // stage Wih1 frags into LDS (linear, coalesced)
  {
    const uint4* src4 = (const uint4*)wih1f;
    uint4* dst4 = (uint4*)lds;
    #pragma unroll
    for(int i=0;i<16;++i) dst4[tid + i*THREADS] = src4[tid + i*THREADS];
  }

  // resident weight fragments (pre-converted, single b128 loads)
  bf16x8 w0h[4][4], w1h[4][4], w0i[4];
  float bias0[4], bias1[4];
  #pragma unroll
  for(int g=0; g<4; ++g){
    #pragma unroll
    for(int ks=0; ks<4; ++ks){
      long off = (long)((((g*8+wv)*4+ks)*64+lane))*8;
      w0h[g][ks] = *(const bf16x8*)(whh0f + off);
      w1h[g][ks] = *(const bf16x8*)(whh1f + off);
    }
    w0i[g] = *(const bf16x8*)(wih0f + (long)(((g*8+wv)*64+lane))*8);
    bias0[g] = biases[g*HID+myc];
    bias1[g] = biases[512 + g*HID+myc];
  }
  float c1[4]={0,0,0,0}, c2[4]={0,0,0,0};
  __syncthreads();   // Wih1 staged

  f32x4 acc1[4];
  for(int tau=0; tau<=SEQ; ++tau){
    const int s_prev = (tau-1)&1;
    // x-frag load (coalesced b128, consumed by layer-0 MFMAs)
    bf16x8 ax;
    if(tau<SEQ) ax = *(const bf16x8*)(xf + (((long)tau*NBLK + blk)*64 + lane)*8);
    // shared A-frags: h1_{tau-1} (layer1 input path AND layer0 recurrence)
    bf16x8 a1[4];
    if(tau>=1){
      #pragma unroll
      for(int ks=0;ks<4;++ks)
        a1[ks] = *(const bf16x8*)(h1r + s_prev*H1SLOT + lr*H1PITCH + ks*32 + lg*8);
    }
    // ---- layer 1 (computes h2_{tau-1}) ----
    if(tau>=1){
      #pragma unroll
      for(int g=0;g<4;++g) acc1[g]=(f32x4){bias1[g],bias1[g],bias1[g],bias1[g]};
      #pragma unroll
      for(int ks=0;ks<4;++ks){
        #pragma unroll
        for(int g=0;g<4;++g){
          bf16x8 wf = *(const bf16x8*)(wihs + (long)((((g*8+wv)*4+ks)*64+lane))*8);
          acc1[g]=__builtin_amdgcn_mfma_f32_16x16x32_bf16(a1[ks],wf,acc1[g],0,0,0);
        }
      }
      if(tau>=2){
        #pragma unroll
        for(int ks=0;ks<4;++ks){
          bf16x8 a2 = *(const bf16x8*)(h2r + (tau&1)*H1SLOT + lr*H1PITCH + ks*32 + lg*8);
          #pragma unroll
          for(int g=0;g<4;++g)
            acc1[g]=__builtin_amdgcn_mfma_f32_16x16x32_bf16(a2,w1h[g][ks],acc1[g],0,0,0);
        }
      }
    }
    // ---- layer 0 (computes h1_tau) ----
    f32x4 acc0[4];
    if(tau<SEQ){
      #pragma unroll
      for(int g=0;g<4;++g){
        acc0[g]=(f32x4){bias0[g],bias0[g],bias0[g],bias0[g]};
        acc0[g]=__builtin_amdgcn_mfma_f32_16x16x32_bf16(ax,w0i[g],acc0[g],0,0,0);
      }
      if(tau>=1){
        #pragma unroll
        for(int ks=0;ks<4;++ks)
          #pragma unroll
          for(int g=0;g<4;++g)
            acc0[g]=__builtin_amdgcn_mfma_f32_16x16x32_bf16(a1[ks],w0h[g][ks],acc0[g],0,0,0);
      }
    }
    // ---- activations + ring writes (two independent chains) ----
    if(tau<SEQ){
      #pragma unroll
      for(int r=0;r<4;++r){
        float iv=sigm(acc0[0][r]), fv=sigm(acc0[1][r]), gv=tanh_(acc0[2][r]), ov=sigm(acc0[3][r]);
        c1[r]=fv*c1[r]+iv*gv;
        h1r[(tau&1)*H1SLOT + (lg*4+r)*H1PITCH + myc] = f2bf(ov*tanh_(c1[r]));
      }
    }
    if(tau>=1){
      #pragma unroll
      for(int r=0;r<4;++r){
        float iv=sigm(acc1[0][r]), fv=sigm(acc1[1][r]), gv=tanh_(acc1[2][r]), ov=sigm(acc1[3][r]);
        c2[r]=fv*c2[r]+iv*gv;
        h2r[s_prev*H1SLOT + (lg*4+r)*H1PITCH + myc] = f2bf(ov*tanh_(c2[r]));
      }
    }
    __syncthreads();
  }

  // ---- FC epilogue on h2_{SEQ-1} (ring slot (SEQ-1)&1 == 1) ----
  f32x4 ay=(f32x4){fcb[myc],fcb[myc],fcb[myc],fcb[myc]};
  #pragma unroll
  for(int ks=0;ks<4;++ks){
    bf16x8 bfc = *(const bf16x8*)(fcf + (long)(((wv*4+ks)*64+lane))*8);
    bf16x8 a2  = *(const bf16x8*)(h2r + 1*H1SLOT + lr*H1PITCH + ks*32 + lg*8);
    ay=__builtin_amdgcn_mfma_f32_16x16x32_bf16(a2,bfc,ay,0,0,0);
  }
  float s=0.f, sq=0.f;
  #pragma unroll
  for(int r=0;r<4;++r){
    float v=ay[r];
    y[(long)(row0+lg*4+r)*HID+myc]=v;
    s+=v; sq+=v*v;
  }
  s +=__shfl_xor(s ,16,64); s +=__shfl_xor(s ,32,64);
  sq+=__shfl_xor(sq,16,64); sq+=__shfl_xor(sq,32,64);
  if(lg==0){
    partial[(long)myc      *NBLK+blk]=s;
    partial[(long)(HID+myc)*NBLK+blk]=sq;
  }
}

// ---------------- BN reduce / apply ----------------
__global__ void bn_reduce(const float* __restrict__ partial, float* __restrict__ mv){
  int c=blockIdx.x;
  float s=0.f,sq=0.f;
  for(int i=threadIdx.x;i<NBLK;i+=256){
    s +=partial[(long)c      *NBLK+i];
    sq+=partial[(long)(HID+c)*NBLK+i];
  }
  #pragma unroll
  for(int m=32;m>=1;m>>=1){ s+=__shfl_xor(s,m,64); sq+=__shfl_xor(sq,m,64); }
  __shared__ float rs[4],rq[4];
  int w=threadIdx.x>>6;
  if((threadIdx.x&63)==0){ rs[w]=s; rq[w]=sq; }
  __syncthreads();
  if(threadIdx.x==0){
    s=rs[0]+rs[1]+rs[2]+rs[3]; sq=rq[0]+rq[1]+rq[2]+rq[3];
    float mean=s/(float)BATCH;
    float var=sq/(float)BATCH-mean*mean;
    mv[c]=mean; mv[HID+c]=rsqrtf(var+1e-5f);
  }
}

__global__ void bn_apply(float* __restrict__ y, const float* __restrict__ mv,
                         const float* __restrict__ gamma, const float* __restrict__ beta){
  long idx=((long)blockIdx.x*256+threadIdx.x)*4;
  int c=(int)(idx&(HID-1));
  float4 v=*reinterpret_cast<float4*>(y+idx);
  v.x=gamma[c+0]*(v.x-mv[c+0])*mv[HID+c+0]+beta[c+0];
  v.y=gamma[c+1]*(v.y-mv[c+1])*mv[HID+c+1]+beta[c+1];
  v.z=gamma[c+2]*(v.z-mv[c+2])*mv[HID+c+2]+beta[c+2];
  v.w=gamma[c+3]*(v.w-mv[c+3])*mv[HID+c+3]+beta[c+3];
  *reinterpret_cast<float4*>(y+idx)=v;
}

extern "C" void kernel_launch(void* const* d_in, const int* in_sizes, int n_in,
                              void* d_out, int out_size, void* d_ws, size_t ws_size,
                              hipStream_t stream){
  const float* x    =(const float*)d_in[0];
  const float* Wih0 =(const float*)d_in[1];
  const float* Whh0 =(const float*)d_in[2];
  const float* bih0 =(const float*)d_in[3];
  const float* bhh0 =(const float*)d_in[4];
  const float* Wih1 =(const float*)d_in[5];
  const float* Whh1 =(const float*)d_in[6];
  const float* bih1 =(const float*)d_in[7];
  const float* bhh1 =(const float*)d_in[8];
  const float* fcW  =(const float*)d_in[9];
  const float* fcb  =(const float*)d_in[10];
  const float* gamma=(const float*)d_in[11];
  const float* beta =(const float*)d_in[12];
  float* y=(float*)d_out;

  // ws layout (bytes)
  char* ws = (char*)d_ws;
  const long XF_BYTES = (long)SEQ*NBLK*64*8*2;              // 62,914,560
  unsigned short* xf    = (unsigned short*)(ws + 0);
  unsigned short* whh0f = (unsigned short*)(ws + XF_BYTES);             // 131072 B
  unsigned short* wih0f = (unsigned short*)(ws + XF_BYTES + 131072);    //  32768 B
  unsigned short* wih1f = (unsigned short*)(ws + XF_BYTES + 163840);    // 131072 B
  unsigned short* whh1f = (unsigned short*)(ws + XF_BYTES + 294912);    // 131072 B
  unsigned short* fcf   = (unsigned short*)(ws + XF_BYTES + 425984);    //  32768 B
  float*          biases= (float*)         (ws + XF_BYTES + 458752);    //   4096 B
  float*          partial=(float*)         (ws + XF_BYTES + 462848);    // 2 MB
  float*          mv    = partial + (long)2*HID*NBLK;

  conv_frag<<<32,256,0,stream>>>(Whh0, whh0f, 4, HID, 4);
  conv_frag<<<8, 256,0,stream>>>(Wih0, wih0f, 4, INP, 1);
  conv_frag<<<32,256,0,stream>>>(Wih1, wih1f, 4, HID, 4);
  conv_frag<<<32,256,0,stream>>>(Whh1, whh1f, 4, HID, 4);
  conv_frag<<<8, 256,0,stream>>>(fcW,  fcf,   1, HID, 4);
  conv_bias<<<4, 256,0,stream>>>(bih0,bhh0,bih1,bhh1,biases);
  stage_x<<<NBLK,256,0,stream>>>(x, xf);

  hipFuncSetAttribute((const void*)lstm_pipe,
                      hipFuncAttributeMaxDynamicSharedMemorySize, LDS_BYTES);
  lstm_pipe<<<NBLK,THREADS,LDS_BYTES,stream>>>(
      xf, whh0f, wih0f, wih1f, whh1f, fcf, biases, fcb, y, partial);
  bn_reduce<<<HID,256,0,stream>>>(partial,mv);
  bn_apply<<<(BATCH*HID)/(256*4),256,0,stream>>>(y,mv,gamma,beta);
}